// Round 8
// baseline (134.127 us; speedup 1.0000x reference)
//
#include <hip/hip_runtime.h>
#include <hip/hip_fp16.h>

// L=8 layers, H=512, K=16 links, N_IN=512, B=8192; out = last 512 cols (fp32).
#define LAYERS 8
#define H      512
#define K      16
#define N_IN   512
#define BATCH  8192
#define R      4      // batch rows per block; 4 x f16 = 8 B -> one ds_read_b64 per gather
#define NT     512    // 8 waves/block; 32 KB LDS -> 4 blocks/CU -> 32 waves/CU (wave cap)
// Layer l gathers from cols [0, 512+512*l); max l=7 -> cols < 4096. Layer 7's
// output is never gathered -> straight to global. LDS = 4096*8 B = 32 KB.
#define LDS_COLS 4096

// Register-budget ledger (hard-won):
//   R3/R4: NT=1024 -> allocator forces 32/36 VGPR + scratch spills. Dead end.
//   R6:    R=4 + prefetch arrays -> rematerialized loads, VGPR=32, 85 us.
//   R7:    R=4, no prefetch, but layer loop FULLY UNROLLED -> scheduler sank
//          param loads next to their gathers, minimized liveness to VGPR=32,
//          exposed L2 latency inside every k-loop (VALUBusy 31%, 73.6 us).
//   Fix:   roll the layer loop (pragma unroll 1). R2 precedent: identical
//          launch bounds + rolled loop -> VGPR=52, params hoisted per layer.

__global__ __launch_bounds__(NT, 4)
void ffn_fused_kernel(const float* __restrict__ x,
                      const int*   __restrict__ link_idx,
                      const float* __restrict__ weights,
                      const float* __restrict__ bias,
                      float*       __restrict__ out)
{
    // vals[c*R + r] = f16 value of column c, block batch-row r.
    __shared__ __align__(16) __half vals[LDS_COLS * R];   // 32768 B

    const int tid  = threadIdx.x;
    const int row0 = blockIdx.x * R;

    // ---- Stage x rows into LDS as f16 (each thread owns one column) ----
    {
        const int c = tid;                     // NT == N_IN == 512
        float v[R];
        #pragma unroll
        for (int r = 0; r < R; ++r)
            v[r] = x[(row0 + r) * N_IN + c];   // coalesced per r
        __half2 p[R / 2];
        #pragma unroll
        for (int r = 0; r < R / 2; ++r)
            p[r] = __floats2half2_rn(v[2 * r], v[2 * r + 1]);
        *(uint2*)&vals[c * R] = *(const uint2*)p;   // one ds_write_b64
    }
    __syncthreads();

    // ---- Layers (each thread owns one h; 4 batch rows in registers) ----
    #pragma unroll 1   // MUST stay rolled: see register-budget ledger above
    for (int l = 0; l < LAYERS; ++l) {
        const int base = (l * H + tid) * K;
        int   idx[K];
        float w[K];
        #pragma unroll
        for (int q = 0; q < 4; ++q) {
            *(int4*)  &idx[4 * q] = ((const int4*)  (link_idx + base))[q];  // 64 B coalesced
            *(float4*)&w  [4 * q] = ((const float4*)(weights  + base))[q];  // 64 B coalesced
        }
        const float b = bias[l * H + tid];

        float acc[R];
        #pragma unroll
        for (int r = 0; r < R; ++r) acc[r] = b;

        #pragma unroll
        for (int k = 0; k < K; ++k) {
            // one ds_read_b64 = 4 rows of column idx[k]
            const uint2 g = *(const uint2*)&vals[idx[k] * R];
            const __half2* hp = (const __half2*)&g;
            const float wk = w[k];
            #pragma unroll
            for (int r = 0; r < R / 2; ++r) {
                const float2 f = __half22float2(hp[r]);   // folds into v_fma_mix_f32
                acc[2 * r]     = fmaf(f.x, wk, acc[2 * r]);
                acc[2 * r + 1] = fmaf(f.y, wk, acc[2 * r + 1]);
            }
        }

        // sigmoid via v_rcp_f32 (~1 ulp) instead of the exact-divide sequence
        #pragma unroll
        for (int r = 0; r < R; ++r)
            acc[r] = __builtin_amdgcn_rcpf(1.0f + __expf(-acc[r]));

        if (l < LAYERS - 1) {
            __half2 p[R / 2];
            #pragma unroll
            for (int r = 0; r < R / 2; ++r)
                p[r] = __floats2half2_rn(acc[2 * r], acc[2 * r + 1]);
            *(uint2*)&vals[(N_IN + l * H + tid) * R] = *(const uint2*)p;  // b64
            __syncthreads();
        } else {
            // final layer: coalesced fp32 stores (lanes -> consecutive h)
            #pragma unroll
            for (int r = 0; r < R; ++r)
                out[(row0 + r) * H + tid] = acc[r];
        }
    }
}

extern "C" void kernel_launch(void* const* d_in, const int* in_sizes, int n_in,
                              void* d_out, int out_size, void* d_ws, size_t ws_size,
                              hipStream_t stream) {
    const float* x        = (const float*)d_in[0];
    const int*   link_idx = (const int*)  d_in[1];
    const float* weights  = (const float*)d_in[2];
    const float* bias     = (const float*)d_in[3];
    float*       out      = (float*)d_out;

    ffn_fused_kernel<<<dim3(BATCH / R), dim3(NT), 0, stream>>>(x, link_idx, weights, bias, out);
}

// Round 9
// 110.678 us; speedup vs baseline: 1.2119x; 1.2119x over previous
//
#include <hip/hip_runtime.h>
#include <hip/hip_fp16.h>

// L=8 layers, H=512, K=16 links, N_IN=512, B=8192; out = last 512 cols (fp32).
#define LAYERS 8
#define H      512
#define K      16
#define N_IN   512
#define BATCH  8192
#define R      8      // batch rows per block; 8 x f16 = 16 B -> one ds_read_b128 per gather
#define NT     512    // 8 waves/block; 64 KB LDS -> 2 blocks/CU -> 16 waves/CU
// Layer l gathers from cols [0, 512+512*l); max l=7 -> cols < 4096. Layer 7's
// output is never gathered -> straight to global. LDS = 4096*16 B = 64 KB.
#define LDS_COLS 4096

// Register-budget ledger:
//   R3/R4 (NT=1024): forced 32/36 VGPR + scratch spills. Dead end.
//   R6/R7/R8 (R=4): VGPR 28-36 w/ remat'd param loads, VALUBusy ~31%, 74-85us.
//   KEY INSIGHT: the backend targets 8 waves/EU (<=64 VGPR) by default; the
//   64 KB LDS cap (2 blocks = 4 waves/EU) is invisible to it. At R=8 the
//   128-VGPR budget is FREE. amdgpu_waves_per_eu(4,4) declares the true
//   occupancy so the scheduler can keep the full gather stream + next-layer
//   param prefetch in flight.

__global__ void __launch_bounds__(NT)
__attribute__((amdgpu_waves_per_eu(4, 4)))
ffn_fused_kernel(const float* __restrict__ x,
                 const int*   __restrict__ link_idx,
                 const float* __restrict__ weights,
                 const float* __restrict__ bias,
                 float*       __restrict__ out)
{
    // vals[c*R + r] = f16 value of column c, block batch-row r.
    __shared__ __align__(16) __half vals[LDS_COLS * R];   // 65536 B

    const int tid  = threadIdx.x;
    const int row0 = blockIdx.x * R;

    // ---- Stage x rows into LDS as f16 (each thread owns one column) ----
    {
        const int c = tid;                     // NT == N_IN == 512
        float v[R];
        #pragma unroll
        for (int r = 0; r < R; ++r)
            v[r] = x[(row0 + r) * N_IN + c];   // coalesced per r
        __half2 p[R / 2];
        #pragma unroll
        for (int r = 0; r < R / 2; ++r)
            p[r] = __floats2half2_rn(v[2 * r], v[2 * r + 1]);
        *(uint4*)&vals[c * R] = *(const uint4*)p;   // one ds_write_b128
    }

    // ---- Preload layer-0 params while LDS staging drains (before barrier) ----
    int   idxA[K]; float wA[K]; float bA;
    {
        const int base = tid * K;              // l=0, h=tid
        #pragma unroll
        for (int q = 0; q < 4; ++q) {
            *(int4*)  &idxA[4 * q] = ((const int4*)  (link_idx + base))[q];
            *(float4*)&wA  [4 * q] = ((const float4*)(weights  + base))[q];
        }
        bA = bias[tid];
    }

    __syncthreads();

    // ---- Layers (each thread owns one h; 8 batch rows in registers) ----
    #pragma unroll
    for (int l = 0; l < LAYERS; ++l) {
        // Prefetch next layer's params under this layer's gather/FMA work.
        int idxB[K]; float wB[K]; float bB = 0.0f;
        if (l < LAYERS - 1) {
            const int nb = ((l + 1) * H + tid) * K;
            #pragma unroll
            for (int q = 0; q < 4; ++q) {
                *(int4*)  &idxB[4 * q] = ((const int4*)  (link_idx + nb))[q];
                *(float4*)&wB  [4 * q] = ((const float4*)(weights  + nb))[q];
            }
            bB = bias[(l + 1) * H + tid];
        }

        float acc[R];
        #pragma unroll
        for (int r = 0; r < R; ++r) acc[r] = bA;

        #pragma unroll
        for (int k = 0; k < K; ++k) {
            // one ds_read_b128 = 8 rows of column idxA[k]
            const uint4 g = *(const uint4*)&vals[idxA[k] * R];
            const __half2* hp = (const __half2*)&g;
            const float wk = wA[k];
            #pragma unroll
            for (int r = 0; r < R / 2; ++r) {
                const float2 f = __half22float2(hp[r]);   // folds into v_fma_mix_f32
                acc[2 * r]     = fmaf(f.x, wk, acc[2 * r]);
                acc[2 * r + 1] = fmaf(f.y, wk, acc[2 * r + 1]);
            }
        }

        // sigmoid via v_rcp_f32 (~1 ulp) instead of the exact-divide sequence
        #pragma unroll
        for (int r = 0; r < R; ++r)
            acc[r] = __builtin_amdgcn_rcpf(1.0f + __expf(-acc[r]));

        if (l < LAYERS - 1) {
            __half2 p[R / 2];
            #pragma unroll
            for (int r = 0; r < R / 2; ++r)
                p[r] = __floats2half2_rn(acc[2 * r], acc[2 * r + 1]);
            *(uint4*)&vals[(N_IN + l * H + tid) * R] = *(const uint4*)p;
            __syncthreads();
            // rotate prefetched params in (full unroll -> register renaming)
            #pragma unroll
            for (int k = 0; k < K; ++k) { idxA[k] = idxB[k]; wA[k] = wB[k]; }
            bA = bB;
        } else {
            // final layer: coalesced fp32 stores (lanes -> consecutive h)
            #pragma unroll
            for (int r = 0; r < R; ++r)
                out[(row0 + r) * H + tid] = acc[r];
        }
    }
}

extern "C" void kernel_launch(void* const* d_in, const int* in_sizes, int n_in,
                              void* d_out, int out_size, void* d_ws, size_t ws_size,
                              hipStream_t stream) {
    const float* x        = (const float*)d_in[0];
    const int*   link_idx = (const int*)  d_in[1];
    const float* weights  = (const float*)d_in[2];
    const float* bias     = (const float*)d_in[3];
    float*       out      = (float*)d_out;

    ffn_fused_kernel<<<dim3(BATCH / R), dim3(NT), 0, stream>>>(x, link_idx, weights, bias, out);
}